// Round 7
// baseline (1999.845 us; speedup 1.0000x reference)
//
#include <hip/hip_runtime.h>
#include <hip/hip_bf16.h>
#include <stdint.h>

// ACT (adaptive computation time) on MI355X.
// R7 = R6 with the compile fix (gemm2 dummy `es` for the dead DO_EMB=0
// branch). Double-buffered K-loops (single barrier per kt) for both GEMMs.
// R5 established: LDS-read-delivery-bound (MfmaUtil 41% vs ~48% LDS ceiling),
// gemm2 at 1 block/CU (grid 256) has zero inter-block latency hiding -> the
// 2-barrier vmcnt(0) drain is fully exposed there. dbuf issues next-kt
// global_load_lds before compute so the pre-barrier drain overlaps ~465 cyc
// of MFMA. LDS 40->80 KB (gemm1 3->2 blocks/CU; emb tile moved LDS->global
// per-kt loads). Numerics unchanged: bf16x3 split (6 products),
// fp32 A staged + register split3 (bit-identical), XCD-pinned swizzle.

#define THR 0.99f
typedef float4 f4;
typedef __attribute__((ext_vector_type(8))) short short8;
typedef __attribute__((ext_vector_type(4))) float f32x4;

__device__ __forceinline__ float ld_in(const void* p, long i, int bf) {
  if (bf) {
    unsigned short u = ((const unsigned short*)p)[i];
    return __uint_as_float(((unsigned int)u) << 16);
  }
  return ((const float*)p)[i];
}
__device__ __forceinline__ f4 ld4(const float* p) { return *(const f4*)p; }

// truncation 3-way bf16 split: x ~= h + m + l, |err| <= 2^-24|x|
__device__ __forceinline__ void split3(float x, unsigned short& h,
                                       unsigned short& m, unsigned short& l) {
  unsigned u = __float_as_uint(x);
  h = (unsigned short)(u >> 16);
  float fh = __uint_as_float(u & 0xFFFF0000u);
  float r = x - fh;  // exact
  unsigned v = __float_as_uint(r);
  m = (unsigned short)(v >> 16);
  float fm = __uint_as_float(v & 0xFFFF0000u);
  l = (unsigned short)(__float_as_uint(r - fm) >> 16);
}

__device__ __forceinline__ void gld16(const void* g, void* l) {
  __builtin_amdgcn_global_load_lds(
      (const __attribute__((address_space(1))) void*)g,
      (__attribute__((address_space(3))) void*)l, 16, 0, 0);
}

// ---------- dtype detect + small param conversion ----------
__global__ void k_detect(const void* mask, int* flag, const void* emb,
                         const void* Wp, const void* bp, const void* b1,
                         const void* b2, float* embF, float* WpF, float* bpF,
                         float* b1F, float* b2F) {
  __shared__ int sbf;
  if (threadIdx.x == 0) {
    unsigned int u = ((const unsigned int*)mask)[0];
    int bf = (u == 0x3F803F80u) ? 1 : 0;  // two bf16 1.0s vs fp32 1.0
    *flag = bf;
    sbf = bf;
  }
  __syncthreads();
  int bf = sbf;
  for (int i = threadIdx.x; i < 11 * 512; i += 256) embF[i] = ld_in(emb, i, bf);
  for (int i = threadIdx.x; i < 512; i += 256) WpF[i] = ld_in(Wp, i, bf);
  for (int i = threadIdx.x; i < 2048; i += 256) b1F[i] = ld_in(b1, i, bf);
  for (int i = threadIdx.x; i < 512; i += 256) b2F[i] = ld_in(b2, i, bf);
  if (threadIdx.x == 0) bpF[0] = ld_in(bp, 0, bf);
}

// ---------- big conversions + weight transpose/split + zero init ----------
__global__ void k_init(const void* state, const void* W1, const void* W2,
                       const void* mask, const int* flag, float* stateF,
                       unsigned short* w1t, unsigned short* w2t, float* maskF,
                       float* prevF, float* hp, float* rem, float* nup,
                       int* counts) {
  int bf = *flag;
  long t = (long)blockIdx.x * blockDim.x + threadIdx.x;
  long st = (long)gridDim.x * blockDim.x;
  for (long i = t; i < 8388608L; i += st) {
    stateF[i] = ld_in(state, i, bf);
    prevF[i] = 0.f;
  }
  // W1 [512][2048] -> W1T planes [2048][512] bf16 x3 (plane stride 1048576)
  for (long i = t; i < 1048576L; i += st) {
    float v = ld_in(W1, i, bf);
    long n = i & 2047, k = i >> 11;
    unsigned short h, m, l;
    split3(v, h, m, l);
    long o = n * 512 + k;
    w1t[o] = h;
    w1t[1048576L + o] = m;
    w1t[2097152L + o] = l;
  }
  // W2 [2048][512] -> W2T planes [512][2048] bf16 x3
  for (long i = t; i < 1048576L; i += st) {
    float v = ld_in(W2, i, bf);
    long k = i >> 9, n = i & 511;
    unsigned short h, m, l;
    split3(v, h, m, l);
    long o = n * 2048 + k;
    w2t[o] = h;
    w2t[1048576L + o] = m;
    w2t[2097152L + o] = l;
  }
  for (long i = t; i < 16384L; i += st) {
    maskF[i] = ld_in(mask, i, bf);
    hp[i] = 0.f;
    rem[i] = 0.f;
    nup[i] = 0.f;
  }
  if (t < 11) counts[t] = 0;
}

// ---------- pondering + halting update + compaction (1 wave / position) ----
__global__ __launch_bounds__(256) void k_ponder(
    const float* __restrict__ stateF, const float* __restrict__ embF,
    const float* __restrict__ WpF, const float* __restrict__ bpF, float* hp,
    float* rem, float* nup, float* uw, int* __restrict__ count,
    int* __restrict__ ridx, int t) {
  int lane = threadIdx.x & 63;
  int pos = blockIdx.x * 4 + (threadIdx.x >> 6);
  float hpv = hp[pos];
  if (hpv >= 1.0f) return;  // halted forever
  const float* s = stateF + (long)pos * 512;
  const float* e = embF + t * 512;
  int d = lane * 8;
  f4 s0 = ld4(s + d), s1 = ld4(s + d + 4);
  f4 e0 = ld4(e + d), e1 = ld4(e + d + 4);
  f4 w0 = ld4(WpF + d), w1 = ld4(WpF + d + 4);
  float acc = (s0.x + e0.x) * w0.x;
  acc = fmaf(s0.y + e0.y, w0.y, acc);
  acc = fmaf(s0.z + e0.z, w0.z, acc);
  acc = fmaf(s0.w + e0.w, w0.w, acc);
  acc = fmaf(s1.x + e1.x, w1.x, acc);
  acc = fmaf(s1.y + e1.y, w1.y, acc);
  acc = fmaf(s1.z + e1.z, w1.z, acc);
  acc = fmaf(s1.w + e1.w, w1.w, acc);
#pragma unroll
  for (int off = 32; off > 0; off >>= 1) acc += __shfl_xor(acc, off, 64);
  if (lane == 0) {
    float p = 1.0f / (1.0f + expf(-(acc + bpF[0])));
    float q = hpv + p;
    float nh = (q > THR) ? 1.0f : 0.0f;
    float st2 = (q <= THR) ? 1.0f : 0.0f;
    float hpn = hpv + p * st2;
    float remn = rem[pos] + nh * (1.0f - hpn);
    hpn = hpn + nh * remn;
    nup[pos] = nup[pos] + st2 + nh;
    uw[pos] = p * st2 + nh * remn;
    hp[pos] = hpn;
    rem[pos] = remn;
    int idx = atomicAdd(count, 1);
    ridx[idx] = pos;
  }
}

#define MFMA16 __builtin_amdgcn_mfma_f32_16x16x32_bf16

// MFMA product loop from buffer BUF: af[3][4] in regs, B planes from LDS.
// products kept: hh, mh, lh, hm, mm, hl (dropped terms <= 2^-24)
#define PROD_LOOP(BUF)                                                         \
  _Pragma("unroll") for (int pb = 0; pb < 3; ++pb) {                           \
    short8 bfr[4];                                                             \
    _Pragma("unroll") for (int nt = 0; nt < 4; ++nt) bfr[nt] =                 \
        *(const short8*)&Bs[BUF][pb][quad][wn + nt * 16 + ln15][0];            \
    int npa = (pb == 0) ? 3 : ((pb == 1) ? 2 : 1);                             \
    for (int pa = 0; pa < npa; ++pa)                                           \
      _Pragma("unroll") for (int mt = 0; mt < 4; ++mt)                         \
          _Pragma("unroll") for (int nt = 0; nt < 4; ++nt) acc[mt][nt] =       \
          MFMA16(af[pa][mt], bfr[nt], acc[mt][nt], 0, 0, 0);                   \
  }

// build af[3][4] from fp32 LDS tile in buffer BUF (+optional emb), reg split3
#define BUILD_AF(BUF, DO_EMB)                                                  \
  short8 af[3][4];                                                             \
  _Pragma("unroll") for (int mt = 0; mt < 4; ++mt) {                           \
    int row = wm + mt * 16 + ln15;                                             \
    f4 x0 = *(const f4*)&Au[BUF][quad][0][row][0];                             \
    f4 x1 = *(const f4*)&Au[BUF][quad][1][row][0];                             \
    float xs[8];                                                               \
    xs[0] = x0.x; xs[1] = x0.y; xs[2] = x0.z; xs[3] = x0.w;                    \
    xs[4] = x1.x; xs[5] = x1.y; xs[6] = x1.z; xs[7] = x1.w;                    \
    if (DO_EMB) {                                                              \
      _Pragma("unroll") for (int j = 0; j < 8; ++j) xs[j] += es[j];            \
    }                                                                          \
    _Pragma("unroll") for (int j = 0; j < 8; ++j) {                            \
      unsigned short h, m, l;                                                  \
      split3(xs[j], h, m, l);                                                  \
      ((unsigned short*)&af[0][mt])[j] = h;                                    \
      ((unsigned short*)&af[1][mt])[j] = m;                                    \
      ((unsigned short*)&af[2][mt])[j] = l;                                    \
    }                                                                          \
  }

// ---------- GEMM1: U = relu((state[ridx]+emb) * W1 + b1) -> U fp32 --------
// A: stateF gathered fp32; B: W1T planes [2048][512]; K=512, N=2048
// XCD swizzle: 2 B-strips per XCD. Double-buffered BK=32, 1 barrier/kt.
__global__ __launch_bounds__(256) void k_gemm1(
    const float* __restrict__ stateF, const float* __restrict__ embT,
    const unsigned short* __restrict__ w1t, const float* __restrict__ b1F,
    const int* __restrict__ count, const int* __restrict__ ridx,
    float* __restrict__ U, int c0, int mc) {
  int Ma = *count;
  int mEnd = c0 + mc;
  if (Ma < mEnd) mEnd = Ma;
  int f = blockIdx.x;
  int x = f & 7, s = f >> 3;
  int n0 = (x * 2 + (s & 1)) * 128;
  int m0 = c0 + (s >> 1) * 128;
  if (m0 >= mEnd) return;
  __shared__ __align__(16) float Au[2][4][2][128][4];           // 2 x 16 KB
  __shared__ __align__(16) unsigned short Bs[2][3][4][128][8];  // 2 x 24 KB
  int tid = threadIdx.x;
  int lane = tid & 63, wv = tid >> 6;
  int quad = lane >> 4, ln15 = lane & 15;
  int wm = (wv >> 1) << 6, wn = (wv & 1) << 6;
  int rr0 = m0 + lane;
  if (rr0 >= mEnd) rr0 = mEnd - 1;
  int rr1 = m0 + 64 + lane;
  if (rr1 >= mEnd) rr1 = mEnd - 1;
  long pos0 = ridx[rr0], pos1 = ridx[rr1];
  f32x4 acc[4][4];
#pragma unroll
  for (int i = 0; i < 4; i++)
#pragma unroll
    for (int j = 0; j < 4; j++) acc[i][j] = (f32x4)0.f;

#define STAGE1(BUF, KT)                                                        \
  {                                                                            \
    _Pragma("unroll") for (int i = 0; i < 4; ++i) {                            \
      int g = wv + 4 * i;                                                      \
      int q = g >> 2, h = (g >> 1) & 1, rh = g & 1;                            \
      long po = rh ? pos1 : pos0;                                              \
      gld16(stateF + po * 512 + (KT) * 32 + q * 8 + h * 4,                     \
            &Au[BUF][q][h][rh * 64][0]);                                       \
    }                                                                          \
    _Pragma("unroll") for (int i = 0; i < 6; ++i) {                            \
      int g = wv + 4 * i;                                                      \
      int p = g >> 3, q = (g >> 1) & 3, rh = g & 1;                            \
      long n = n0 + rh * 64 + lane;                                            \
      gld16(w1t + (long)p * 1048576L + n * 512 + (KT) * 32 + q * 8,           \
            &Bs[BUF][p][q][rh * 64][0]);                                       \
    }                                                                          \
  }

  STAGE1(0, 0);
  __syncthreads();
#pragma unroll 1
  for (int kt = 0; kt < 16; ++kt) {
    int cur = kt & 1;
    if (kt + 1 < 16) STAGE1(cur ^ 1, kt + 1);
    float es[8];
    {
      f4 e0 = ld4(embT + kt * 32 + quad * 8);
      f4 e1 = ld4(embT + kt * 32 + quad * 8 + 4);
      es[0] = e0.x; es[1] = e0.y; es[2] = e0.z; es[3] = e0.w;
      es[4] = e1.x; es[5] = e1.y; es[6] = e1.z; es[7] = e1.w;
    }
    BUILD_AF(cur, 1);
    PROD_LOOP(cur);
    __syncthreads();
  }
#pragma unroll
  for (int mt = 0; mt < 4; ++mt)
#pragma unroll
    for (int reg = 0; reg < 4; ++reg) {
      int r = m0 + wm + mt * 16 + quad * 4 + reg;
      if (r < mEnd) {
        long lr = r - c0;
#pragma unroll
        for (int nt = 0; nt < 4; ++nt) {
          int n = n0 + wn + nt * 16 + ln15;
          U[lr * 2048 + n] = fmaxf(acc[mt][nt][reg] + b1F[n], 0.f);
        }
      }
    }
}

// ---------- GEMM2: h = U*W2 + b2; state=h*mask; prev += h*uw --------------
// A: U fp32 [Mc][2048] local rows; B: W2T planes [512][2048]; K=2048, N=512
// XCD swizzle: one 128-col strip per XCD pair. Double-buffered BK=32.
__global__ __launch_bounds__(256) void k_gemm2(
    const float* __restrict__ U, const unsigned short* __restrict__ w2t,
    const float* __restrict__ b2F, const int* __restrict__ count,
    const int* __restrict__ ridx, const float* __restrict__ maskF,
    const float* __restrict__ uwF, float* __restrict__ stateF,
    float* __restrict__ prevF, int c0, int mc) {
  int Ma = *count;
  int mEnd = c0 + mc;
  if (Ma < mEnd) mEnd = Ma;
  int f = blockIdx.x;
  int x = f & 7, s = f >> 3;
  int n0 = (x >> 1) * 128;
  int m0 = c0 + (s * 2 + (x & 1)) * 128;
  if (m0 >= mEnd) return;
  __shared__ __align__(16) float Au[2][4][2][128][4];           // 2 x 16 KB
  __shared__ __align__(16) unsigned short Bs[2][3][4][128][8];  // 2 x 24 KB
  int tid = threadIdx.x;
  int lane = tid & 63, wv = tid >> 6;
  int quad = lane >> 4, ln15 = lane & 15;
  int wm = (wv >> 1) << 6, wn = (wv & 1) << 6;
  long lr0 = (long)(m0 - c0) + lane;
  long lr1 = lr0 + 64;
  f32x4 acc[4][4];
#pragma unroll
  for (int i = 0; i < 4; i++)
#pragma unroll
    for (int j = 0; j < 4; j++) acc[i][j] = (f32x4)0.f;

#define STAGE2(BUF, KT)                                                        \
  {                                                                            \
    _Pragma("unroll") for (int i = 0; i < 4; ++i) {                            \
      int g = wv + 4 * i;                                                      \
      int q = g >> 2, h = (g >> 1) & 1, rh = g & 1;                            \
      long lr = rh ? lr1 : lr0;                                                \
      gld16(U + lr * 2048 + (KT) * 32 + q * 8 + h * 4,                         \
            &Au[BUF][q][h][rh * 64][0]);                                       \
    }                                                                          \
    _Pragma("unroll") for (int i = 0; i < 6; ++i) {                            \
      int g = wv + 4 * i;                                                      \
      int p = g >> 3, q = (g >> 1) & 3, rh = g & 1;                            \
      long n = n0 + rh * 64 + lane;                                            \
      gld16(w2t + (long)p * 1048576L + n * 2048 + (KT) * 32 + q * 8,          \
            &Bs[BUF][p][q][rh * 64][0]);                                       \
    }                                                                          \
  }

  STAGE2(0, 0);
  __syncthreads();
#pragma unroll 1
  for (int kt = 0; kt < 64; ++kt) {
    int cur = kt & 1;
    if (kt + 1 < 64) STAGE2(cur ^ 1, kt + 1);
    float es[8] = {0.f, 0.f, 0.f, 0.f, 0.f, 0.f, 0.f, 0.f};  // dead (DO_EMB=0)
    (void)es;
    BUILD_AF(cur, 0);
    PROD_LOOP(cur);
    __syncthreads();
  }
#pragma unroll
  for (int mt = 0; mt < 4; ++mt)
#pragma unroll
    for (int reg = 0; reg < 4; ++reg) {
      int r = m0 + wm + mt * 16 + quad * 4 + reg;
      if (r < mEnd) {
        long pos = (long)ridx[r];
        float mk = maskF[pos];
        float uv = uwF[pos];
#pragma unroll
        for (int nt = 0; nt < 4; ++nt) {
          int n = n0 + wn + nt * 16 + ln15;
          float h = (acc[mt][nt][reg] + b2F[n]) * mk;
          long off = pos * 512 + n;
          stateF[off] = h;
          prevF[off] = fmaf(h, uv, prevF[off]);
        }
      }
    }
}

// ---------- final: concat outputs, cast per detected dtype ----------
__global__ void k_final(const float* prevF, const float* nupF,
                        const float* remF, void* out, const int* flag) {
  long i = (long)blockIdx.x * 256 + threadIdx.x;
  if (i >= 8421376L) return;
  float v;
  if (i < 8388608L) v = prevF[i];
  else if (i < 8404992L) v = nupF[i - 8388608L];
  else v = remF[i - 8404992L];
  if (*flag) ((__hip_bfloat16*)out)[i] = __float2bfloat16(v);
  else ((float*)out)[i] = v;
}

extern "C" void kernel_launch(void* const* d_in, const int* in_sizes, int n_in,
                              void* d_out, int out_size, void* d_ws,
                              size_t ws_size, hipStream_t stream) {
  const void* state = d_in[0];
  const void* mask = d_in[1];
  const void* emb = d_in[2];
  const void* Wp = d_in[3];
  const void* bp = d_in[4];
  const void* W1 = d_in[5];
  const void* b1 = d_in[6];
  const void* W2 = d_in[7];
  const void* b2 = d_in[8];
  char* w = (char*)d_ws;
  float* stateF = (float*)(w + 0L);
  float* prevF = (float*)(w + 33554432L);
  unsigned short* w1t = (unsigned short*)(w + 67108864L);  // 3 x 2 MB
  unsigned short* w2t = (unsigned short*)(w + 73400320L);  // 3 x 2 MB
  float* maskF = (float*)(w + 79691776L);
  float* hp = (float*)(w + 79757312L);
  float* rem = (float*)(w + 79822848L);
  float* nup = (float*)(w + 79888384L);
  float* uwf = (float*)(w + 79953920L);
  float* embF = (float*)(w + 80019456L);
  float* WpF = (float*)(w + 80052224L);
  float* b1F = (float*)(w + 80056320L);
  float* b2F = (float*)(w + 80064512L);
  float* bpF = (float*)(w + 80068608L);
  int* flag = (int*)(w + 80068864L);
  int* counts = (int*)(w + 80069120L);
  int* ridx = (int*)(w + 80070144L);  // 11 x 16384 x 4 B
  float* U = (float*)(w + 80791040L); // fp32 [Mc][2048]
  long ub = (long)ws_size - 80791040L;
  long rows = ub / 8192L;
  long McL = rows & ~255L;  // multiple of 256 so T=mc/128 stays even
  if (McL > 16384L) McL = 16384L;
  if (McL < 256L) McL = 256L;
  int Mc = (int)McL;
  int nCh = (16384 + Mc - 1) / Mc;

  k_detect<<<1, 256, 0, stream>>>(mask, flag, emb, Wp, bp, b1, b2, embF, WpF,
                                  bpF, b1F, b2F);
  k_init<<<2048, 256, 0, stream>>>(state, W1, W2, mask, flag, stateF, w1t, w2t,
                                   maskF, prevF, hp, rem, nup, counts);
  for (int t = 0; t <= 10; t++) {
    k_ponder<<<4096, 256, 0, stream>>>(stateF, embF, WpF, bpF, hp, rem, nup,
                                       uwf, counts + t, ridx + (long)t * 16384,
                                       t);
    for (int c = 0; c < nCh; c++) {
      int c0 = c * Mc;
      int mc = 16384 - c0;
      if (mc > Mc) mc = Mc;
      int T = mc / 128;  // even (Mc multiple of 256, 16384 multiple of 256)
      k_gemm1<<<T * 16, 256, 0, stream>>>(stateF, embF + t * 512, w1t, b1F,
                                          counts + t, ridx + (long)t * 16384,
                                          U, c0, mc);
      k_gemm2<<<T * 4, 256, 0, stream>>>(U, w2t, b2F, counts + t,
                                         ridx + (long)t * 16384, maskF, uwf,
                                         stateF, prevF, c0, mc);
    }
  }
  k_final<<<32896, 256, 0, stream>>>(prevF, nup, rem, d_out, flag);
}